// Round 2
// baseline (195.770 us; speedup 1.0000x reference)
//
#include <hip/hip_runtime.h>

#define BS    128
#define NF    4
#define P_LO  1024
#define P_HI  16384
#define KNN   9
#define THREADS 256

__global__ __launch_bounds__(THREADS) void rect_up_kernel(
    const float* __restrict__ x,       // (BS, NF*P_LO) f32
    const int*   __restrict__ cls_ids, // (BS,)
    const int*   __restrict__ nbr,     // (P_HI, K) int32
    const float* __restrict__ wmap,    // (NC, NF, P_HI, K) f32
    const float* __restrict__ blo,     // (NC, NF, P_LO) f32
    const float* __restrict__ bhi,     // (NC, NF, P_HI) f32
    float*       __restrict__ out)     // (BS, NF, P_HI) f32
{
    __shared__ float ylds[P_LO];

    const int b   = blockIdx.x >> 2;
    const int f   = blockIdx.x & 3;
    const int cls = cls_ids[b];
    const int tid = threadIdx.x;

    // ---- stage y_low_db = x[b,f,:] - bias_low[cls,f,:] into LDS ----
    const float4* xp4  = (const float4*)(x   + (b   * NF + f) * P_LO);
    const float4* blp4 = (const float4*)(blo + (cls * NF + f) * P_LO);
    {
        // 1024 floats = 256 float4s, one per thread
        float4 xv = xp4[tid];
        float4 bv = blp4[tid];
        float4 r;
        r.x = xv.x - bv.x; r.y = xv.y - bv.y;
        r.z = xv.z - bv.z; r.w = xv.w - bv.w;
        ((float4*)ylds)[tid] = r;
    }
    __syncthreads();

    const float* wbase = wmap + (size_t)(cls * NF + f) * P_HI * KNN;
    const float* bhp   = bhi  + (size_t)(cls * NF + f) * P_HI;
    float*       op    = out  + (size_t)(b   * NF + f) * P_HI;

    // each thread processes pairs of consecutive p: pp in [0, P_HI/2)
    #pragma unroll 4
    for (int pp = tid; pp < P_HI / 2; pp += THREADS) {
        const int p0 = pp * 2;

        // 18 neighbor indices (p0 and p0+1), 72B chunk, 8B-aligned
        const int2* ip = (const int2*)(nbr + (size_t)p0 * KNN);
        int idx[18];
        #pragma unroll
        for (int j = 0; j < 9; ++j) {
            int2 v = ip[j];
            idx[2 * j]     = v.x;
            idx[2 * j + 1] = v.y;
        }

        // 18 weights, 72B chunk, 8B-aligned -> 9 float2 loads
        const float2* wp = (const float2*)(wbase + (size_t)p0 * KNN);
        float w[18];
        #pragma unroll
        for (int j = 0; j < 9; ++j) {
            float2 v = wp[j];
            w[2 * j]     = v.x;
            w[2 * j + 1] = v.y;
        }

        float acc0 = 0.f, acc1 = 0.f;
        #pragma unroll
        for (int k = 0; k < 9; ++k) acc0 = fmaf(w[k],     ylds[idx[k]],     acc0);
        #pragma unroll
        for (int k = 0; k < 9; ++k) acc1 = fmaf(w[9 + k], ylds[idx[9 + k]], acc1);

        float2 bh = *(const float2*)(bhp + p0);
        float2 o;
        o.x = acc0 + bh.x;
        o.y = acc1 + bh.y;
        *(float2*)(op + p0) = o;
    }
}

extern "C" void kernel_launch(void* const* d_in, const int* in_sizes, int n_in,
                              void* d_out, int out_size, void* d_ws, size_t ws_size,
                              hipStream_t stream) {
    const float* x    = (const float*)d_in[0];
    const int*   cls  = (const int*)d_in[1];
    const int*   nbr  = (const int*)d_in[2];
    const float* wmap = (const float*)d_in[3];
    const float* blo  = (const float*)d_in[4];
    const float* bhi  = (const float*)d_in[5];
    float*       out  = (float*)d_out;

    dim3 grid(BS * NF);
    rect_up_kernel<<<grid, THREADS, 0, stream>>>(x, cls, nbr, wmap, blo, bhi, out);
}

// Round 3
// 191.602 us; speedup vs baseline: 1.0218x; 1.0218x over previous
//
#include <hip/hip_runtime.h>

#define BS      128
#define NF      4
#define P_LO    1024
#define P_HI    16384
#define KNN     9
#define THREADS 256
#define CHUNKS  4                    // blocks per (b,f) plane
#define CHUNK_P (P_HI / CHUNKS)      // 4096 p per block

__global__ __launch_bounds__(THREADS) void rect_up_kernel(
    const float* __restrict__ x,       // (BS, NF*P_LO) f32
    const int*   __restrict__ cls_ids, // (BS,)
    const int*   __restrict__ nbr,     // (P_HI, K) int32
    const float* __restrict__ wmap,    // (NC, NF, P_HI, K) f32
    const float* __restrict__ blo,     // (NC, NF, P_LO) f32
    const float* __restrict__ bhi,     // (NC, NF, P_HI) f32
    float*       __restrict__ out)     // (BS, NF, P_HI) f32
{
    __shared__ float ylds[P_LO];

    // blockIdx.x = ((b*NF + f) * CHUNKS) + chunk
    const int bf    = blockIdx.x / CHUNKS;
    const int chunk = blockIdx.x % CHUNKS;
    const int b     = bf >> 2;
    const int f     = bf & 3;
    const int cls   = cls_ids[b];
    const int tid   = threadIdx.x;

    // ---- stage y_low_db = x[b,f,:] - bias_low[cls,f,:] into LDS ----
    const float4* xp4  = (const float4*)(x   + (b   * NF + f) * P_LO);
    const float4* blp4 = (const float4*)(blo + (cls * NF + f) * P_LO);
    {
        // 1024 floats = 256 float4s, one per thread
        float4 xv = xp4[tid];
        float4 bv = blp4[tid];
        float4 r;
        r.x = xv.x - bv.x; r.y = xv.y - bv.y;
        r.z = xv.z - bv.z; r.w = xv.w - bv.w;
        ((float4*)ylds)[tid] = r;
    }
    __syncthreads();

    const float* wbase = wmap + (size_t)(cls * NF + f) * P_HI * KNN;
    const float* bhp   = bhi  + (size_t)(cls * NF + f) * P_HI;
    float*       op    = out  + (size_t)(b   * NF + f) * P_HI;

    // this block covers pp in [chunk*CHUNK_P/2, (chunk+1)*CHUNK_P/2)
    const int pp_lo = chunk * (CHUNK_P / 2);
    const int pp_hi = pp_lo + (CHUNK_P / 2);

    #pragma unroll 4
    for (int pp = pp_lo + tid; pp < pp_hi; pp += THREADS) {
        const int p0 = pp * 2;

        // 18 neighbor indices (p0 and p0+1), 72B chunk, 8B-aligned
        const int2* ip = (const int2*)(nbr + (size_t)p0 * KNN);
        int idx[18];
        #pragma unroll
        for (int j = 0; j < 9; ++j) {
            int2 v = ip[j];
            idx[2 * j]     = v.x;
            idx[2 * j + 1] = v.y;
        }

        // 18 weights, 72B chunk, 8B-aligned -> 9 float2 loads
        const float2* wp = (const float2*)(wbase + (size_t)p0 * KNN);
        float w[18];
        #pragma unroll
        for (int j = 0; j < 9; ++j) {
            float2 v = wp[j];
            w[2 * j]     = v.x;
            w[2 * j + 1] = v.y;
        }

        float acc0 = 0.f, acc1 = 0.f;
        #pragma unroll
        for (int k = 0; k < 9; ++k) acc0 = fmaf(w[k],     ylds[idx[k]],     acc0);
        #pragma unroll
        for (int k = 0; k < 9; ++k) acc1 = fmaf(w[9 + k], ylds[idx[9 + k]], acc1);

        float2 bh = *(const float2*)(bhp + p0);
        float2 o;
        o.x = acc0 + bh.x;
        o.y = acc1 + bh.y;
        *(float2*)(op + p0) = o;
    }
}

extern "C" void kernel_launch(void* const* d_in, const int* in_sizes, int n_in,
                              void* d_out, int out_size, void* d_ws, size_t ws_size,
                              hipStream_t stream) {
    const float* x    = (const float*)d_in[0];
    const int*   cls  = (const int*)d_in[1];
    const int*   nbr  = (const int*)d_in[2];
    const float* wmap = (const float*)d_in[3];
    const float* blo  = (const float*)d_in[4];
    const float* bhi  = (const float*)d_in[5];
    float*       out  = (float*)d_out;

    dim3 grid(BS * NF * CHUNKS);
    rect_up_kernel<<<grid, THREADS, 0, stream>>>(x, cls, nbr, wmap, blo, bhi, out);
}

// Round 4
// 179.413 us; speedup vs baseline: 1.0912x; 1.0679x over previous
//
#include <hip/hip_runtime.h>

#define BS      128
#define NF      4
#define P_LO    1024
#define P_HI    16384
#define KNN     9
#define THREADS 256
#define CHUNKS  8
#define CHUNK_P (P_HI / CHUNKS)       // 2048 p per block
#define TILE_P  128                   // p per wave-pass
#define TILE_F  (TILE_P * KNN)        // 1152 flat elems per tile
#define WAVES   (THREADS / 64)

__global__ __launch_bounds__(THREADS) void rect_up_kernel(
    const float* __restrict__ x,       // (BS, NF*P_LO) f32
    const int*   __restrict__ cls_ids, // (BS,)
    const int*   __restrict__ nbr,     // (P_HI, K) int32
    const float* __restrict__ wmap,    // (NC, NF, P_HI, K) f32
    const float* __restrict__ blo,     // (NC, NF, P_LO) f32
    const float* __restrict__ bhi,     // (NC, NF, P_HI) f32
    float*       __restrict__ out)     // (BS, NF, P_HI) f32
{
    __shared__ float ylds[P_LO];
    __shared__ float prod[WAVES][TILE_F];   // wave-private product buffers

    // blockIdx.x = ((b*NF + f) * CHUNKS) + chunk
    const int bf    = blockIdx.x / CHUNKS;
    const int chunk = blockIdx.x % CHUNKS;
    const int b     = bf >> 2;
    const int f     = bf & 3;
    const int cls   = cls_ids[b];
    const int tid   = threadIdx.x;
    const int wave  = tid >> 6;
    const int lane  = tid & 63;

    // ---- stage y_low_db = x[b,f,:] - bias_low[cls,f,:] into LDS ----
    {
        const float4* xp4  = (const float4*)(x   + (b   * NF + f) * P_LO);
        const float4* blp4 = (const float4*)(blo + (cls * NF + f) * P_LO);
        float4 xv = xp4[tid];          // 1024 floats = 256 float4, one each
        float4 bv = blp4[tid];
        float4 r;
        r.x = xv.x - bv.x; r.y = xv.y - bv.y;
        r.z = xv.z - bv.z; r.w = xv.w - bv.w;
        ((float4*)ylds)[tid] = r;
    }
    __syncthreads();

    const float* wbase = wmap + (size_t)(cls * NF + f) * P_HI * KNN;
    const float* bhp   = bhi  + (size_t)(cls * NF + f) * P_HI;
    float*       op    = out  + (size_t)(b   * NF + f) * P_HI;
    float*       pbuf  = prod[wave];

    const int tiles = CHUNK_P / TILE_P;        // 16 tiles per block
    for (int t = wave; t < tiles; t += WAVES) {
        const int    ptile = chunk * CHUNK_P + t * TILE_P;
        const size_t fbase = (size_t)ptile * KNN;

        // ---- phase A: coalesced flat loads, gather, multiply, scatter ----
        #pragma unroll
        for (int j = 0; j < KNN; ++j) {
            const int off = j * 128 + 2 * lane;           // flat elem offset
            int2   i2 = *(const int2*)  (nbr   + fbase + off);  // coalesced
            float2 w2 = *(const float2*)(wbase + fbase + off);  // coalesced
            float2 pr;
            pr.x = w2.x * ylds[i2.x];
            pr.y = w2.y * ylds[i2.y];
            *(float2*)(pbuf + off) = pr;                  // conflict-free
        }

        // ---- phase B: per-lane readback (18 contiguous) + reduce 9+9 ----
        // per-wave LDS ops are in-order; compiler inserts lgkmcnt waits
        float2 r[9];
        #pragma unroll
        for (int j = 0; j < 9; ++j)
            r[j] = *(const float2*)(pbuf + lane * 18 + 2 * j);  // 8B-aligned

        float a0 = r[0].x + r[0].y + r[1].x + r[1].y + r[2].x + r[2].y
                 + r[3].x + r[3].y + r[4].x;
        float a1 = r[4].y + r[5].x + r[5].y + r[6].x + r[6].y
                 + r[7].x + r[7].y + r[8].x + r[8].y;

        const int pp = ptile + 2 * lane;
        float2 bh = *(const float2*)(bhp + pp);           // coalesced
        float2 o;
        o.x = a0 + bh.x;
        o.y = a1 + bh.y;
        *(float2*)(op + pp) = o;                          // coalesced
    }
}

extern "C" void kernel_launch(void* const* d_in, const int* in_sizes, int n_in,
                              void* d_out, int out_size, void* d_ws, size_t ws_size,
                              hipStream_t stream) {
    const float* x    = (const float*)d_in[0];
    const int*   cls  = (const int*)d_in[1];
    const int*   nbr  = (const int*)d_in[2];
    const float* wmap = (const float*)d_in[3];
    const float* blo  = (const float*)d_in[4];
    const float* bhi  = (const float*)d_in[5];
    float*       out  = (float*)d_out;

    dim3 grid(BS * NF * CHUNKS);
    rect_up_kernel<<<grid, THREADS, 0, stream>>>(x, cls, nbr, wmap, blo, bhi, out);
}

// Round 5
// 166.993 us; speedup vs baseline: 1.1723x; 1.0744x over previous
//
#include <hip/hip_runtime.h>

#define BS      128
#define NF      4
#define NC      36
#define P_LO    1024
#define P_HI    16384
#define KNN     9
#define THREADS 256
#define TILE_P  512
#define TILE_F  (TILE_P * KNN)      // 4608 flat elems per tile
#define NTILES  (P_HI / TILE_P)     // 32
#define LIST_OFF 64                 // ints; ws[0..35]=counts, ws[64+c*128+i]=sample ids

// ---- pre-pass: bucket samples by class into workspace ----
__global__ __launch_bounds__(128) void build_lists_kernel(
    const int* __restrict__ cls_ids, int* __restrict__ ws)
{
    __shared__ int cnt[NC];
    const int t = threadIdx.x;
    if (t < NC) cnt[t] = 0;
    __syncthreads();
    if (t < BS) {
        int c = cls_ids[t];
        int pos = atomicAdd(&cnt[c], 1);
        ws[LIST_OFF + c * BS + pos] = t;
    }
    __syncthreads();
    if (t < NC) ws[t] = cnt[t];
}

// ---- main: block = (cls, f, tile); loop over samples of cls ----
__global__ __launch_bounds__(THREADS) void rect_up_kernel(
    const float* __restrict__ x,       // (BS, NF*P_LO)
    const int*   __restrict__ ws,      // counts + lists
    const int*   __restrict__ nbr,     // (P_HI, K)
    const float* __restrict__ wmap,    // (NC, NF, P_HI, K)
    const float* __restrict__ blo,     // (NC, NF, P_LO)
    const float* __restrict__ bhi,     // (NC, NF, P_HI)
    float*       __restrict__ out)     // (BS, NF, P_HI)
{
    __shared__ __align__(16) char smem[TILE_F * 4 * 2];       // 36864 B
    float* w_st = (float*)smem;
    int*   i_st = (int*)(smem + TILE_F * 4);
    float* ybuf = (float*)(smem + TILE_F * 4);  // overlays i_st after readback

    const int tile = blockIdx.x % NTILES;
    const int cf   = blockIdx.x / NTILES;
    const int f    = cf % NF;
    const int cls  = cf / NF;

    const int n_b = ws[cls];
    if (n_b == 0) return;              // uniform exit, before any __syncthreads

    const int tid   = threadIdx.x;
    const int tbase = tile * TILE_P;

    // stage w + idx for this tile, fully coalesced
    const float4* wsrc = (const float4*)(wmap + ((size_t)(cls * NF + f) * P_HI + tbase) * KNN);
    const int4*   isrc = (const int4*)(nbr + (size_t)tbase * KNN);
    float4* w4 = (float4*)w_st;
    int4*   i4 = (int4*)i_st;
    #pragma unroll
    for (int i = tid; i < TILE_F / 4; i += THREADS) {   // 1152 float4s
        w4[i] = wsrc[i];
        i4[i] = isrc[i];
    }
    __syncthreads();

    // readback to registers: thread owns p0 = tbase+2*tid and p0+1
    float w[18]; int nb[18];
    {
        const float2* wr = (const float2*)w_st + (size_t)tid * 9;
        const int2*   ir = (const int2*)i_st + (size_t)tid * 9;
        #pragma unroll
        for (int j = 0; j < 9; ++j) {
            float2 a = wr[j]; w[2 * j] = a.x; w[2 * j + 1] = a.y;
            int2   c = ir[j]; nb[2 * j] = c.x; nb[2 * j + 1] = c.y;
        }
    }
    __syncthreads();                   // i_st now dead -> reuse as ybuf

    // per-block constants in registers
    const int    p0 = tbase + 2 * tid;
    const float2 bh = *(const float2*)(bhi + (size_t)(cls * NF + f) * P_HI + p0);
    const float4 bl = ((const float4*)(blo + (cls * NF + f) * P_LO))[tid];
    const int*  list = ws + LIST_OFF + cls * BS;

    // prologue: stage sample 0 into ybuf[0]
    {
        const int b = list[0];
        float4 xv = ((const float4*)(x + (b * NF + f) * P_LO))[tid];
        float4 r;
        r.x = xv.x - bl.x; r.y = xv.y - bl.y;
        r.z = xv.z - bl.z; r.w = xv.w - bl.w;
        ((float4*)ybuf)[tid] = r;
    }

    for (int s = 0; s < n_b; ++s) {
        __syncthreads();               // ybuf[s&1] ready
        const float* y = ybuf + (s & 1) * P_LO;
        if (s + 1 < n_b) {             // prefetch next sample's plane
            const int b1 = list[s + 1];
            float4 xv = ((const float4*)(x + (b1 * NF + f) * P_LO))[tid];
            float4 r;
            r.x = xv.x - bl.x; r.y = xv.y - bl.y;
            r.z = xv.z - bl.z; r.w = xv.w - bl.w;
            ((float4*)(ybuf + ((s + 1) & 1) * P_LO))[tid] = r;
        }
        const int b = list[s];
        float a0 = 0.f, a1 = 0.f;
        #pragma unroll
        for (int k = 0; k < 9; ++k) a0 = fmaf(w[k],     y[nb[k]],     a0);
        #pragma unroll
        for (int k = 0; k < 9; ++k) a1 = fmaf(w[9 + k], y[nb[9 + k]], a1);
        float2 o;
        o.x = a0 + bh.x;
        o.y = a1 + bh.y;
        *(float2*)(out + (size_t)(b * NF + f) * P_HI + p0) = o;
    }
}

extern "C" void kernel_launch(void* const* d_in, const int* in_sizes, int n_in,
                              void* d_out, int out_size, void* d_ws, size_t ws_size,
                              hipStream_t stream) {
    const float* x    = (const float*)d_in[0];
    const int*   cls  = (const int*)d_in[1];
    const int*   nbr  = (const int*)d_in[2];
    const float* wmap = (const float*)d_in[3];
    const float* blo  = (const float*)d_in[4];
    const float* bhi  = (const float*)d_in[5];
    float*       out  = (float*)d_out;
    int*         wsl  = (int*)d_ws;   // needs (64 + 36*128)*4 = 18.7 KB

    build_lists_kernel<<<1, 128, 0, stream>>>(cls, wsl);
    rect_up_kernel<<<NC * NF * NTILES, THREADS, 0, stream>>>(
        x, wsl, nbr, wmap, blo, bhi, out);
}